// Round 8
// baseline (530.976 us; speedup 1.0000x reference)
//
#include <hip/hip_runtime.h>

// AVWGCN: out[b,n,o] = sum_k sum_i xg_k[b,n,i] * w[k,i,o] + bias[o]
//   xg0 = x, xg1 = S@x, xg2 = 2*S@(S@x) - x   (S = softmax(relu(adj@emb), rows))
// Algebra: never form T2; fold "2*" and "-x" into Wcat = [w0-w2 | w1 | 2*w2].
// GEMM: 128x128 tile, BK=64, 4 waves (2x2), 64 KiB LDS dbuf -> TWO blocks/CU
// (m114 mechanism: independent barrier gangs overlap each other's stalls; the
// 256d/128KB version was 1 block/CU and plateaued at 137 µs across all schedule
// variants). Round-3 8-region counted-vmcnt schedule, scaled to mfma8/region.
// Round-7's epilogue fusion reverted (serial epilogue at 1 blk/CU lost 23 µs).

typedef __bf16 bf16;
typedef __bf16 bf16x8 __attribute__((ext_vector_type(8)));
typedef float f32x4 __attribute__((ext_vector_type(4)));

__device__ __forceinline__ void async_lds16(const void* g, void* l) {
  __builtin_amdgcn_global_load_lds((const __attribute__((address_space(1))) void*)g,
                                   (__attribute__((address_space(3))) void*)l, 16, 0, 0);
}

#define FENCE() asm volatile("" ::: "memory")
#define BAR()                          \
  do {                                 \
    FENCE();                           \
    __builtin_amdgcn_s_barrier();      \
    FENCE();                           \
  } while (0)
#define WAIT_VM(n) asm volatile("s_waitcnt vmcnt(" #n ")" ::: "memory")

// ---- S rows softmax(relu(adj@emb)) + (blocks 0..47) Wcat build fused ----
// Wcat[o][kk] bf16, kk in [0,192): [w0-w2 | w1 | 2*w2] transposed to o-rows.
__global__ __launch_bounds__(256) void supports_k(const float* __restrict__ adj,
                                                  const float* __restrict__ emb,
                                                  bf16* __restrict__ S,
                                                  const float* __restrict__ w,
                                                  bf16* __restrict__ Wc) {
  const int tid = threadIdx.x;
  {  // fused wcat: 64*192 = 12288 elems over blocks 0..47
    const int idx = blockIdx.x * 256 + tid;
    if (idx < 64 * 192) {
      const int o = idx / 192, kk = idx - o * 192;
      const int k = kk >> 6, i = kk & 63;
      float v;
      if (k == 0)      v = w[i * 64 + o] - w[2 * 4096 + i * 64 + o];
      else if (k == 1) v = w[4096 + i * 64 + o];
      else             v = 2.f * w[2 * 4096 + i * 64 + o];
      Wc[idx] = (bf16)v;
    }
  }
  __shared__ float slog[8][4096];  // 128 KiB logit stash
  __shared__ float sadj[8][16];
  __shared__ float swred[4][8];
  const int lane = tid & 63, wv = tid >> 6;
  const int n0 = blockIdx.x * 8;
  if (tid < 128) sadj[tid >> 4][tid & 15] = adj[n0 * 16 + tid];
  __syncthreads();

  float mx[8];
  #pragma unroll
  for (int r = 0; r < 8; ++r) mx[r] = 0.f;  // relu => max >= 0

  for (int it = 0; it < 16; ++it) {
    const int j = it * 256 + tid;
    float e[16];
    #pragma unroll
    for (int k = 0; k < 16; ++k) e[k] = emb[k * 4096 + j];
    #pragma unroll
    for (int r = 0; r < 8; ++r) {
      float v = 0.f;
      #pragma unroll
      for (int k = 0; k < 16; ++k) v = fmaf(sadj[r][k], e[k], v);
      v = fmaxf(v, 0.f);
      slog[r][j] = v;
      mx[r] = fmaxf(mx[r], v);
    }
  }
  #pragma unroll
  for (int r = 0; r < 8; ++r) {
    #pragma unroll
    for (int off = 32; off > 0; off >>= 1) mx[r] = fmaxf(mx[r], __shfl_xor(mx[r], off, 64));
  }
  if (lane == 0) {
    #pragma unroll
    for (int r = 0; r < 8; ++r) swred[wv][r] = mx[r];
  }
  __syncthreads();
  #pragma unroll
  for (int r = 0; r < 8; ++r)
    mx[r] = fmaxf(fmaxf(swred[0][r], swred[1][r]), fmaxf(swred[2][r], swred[3][r]));

  float sm[8];
  #pragma unroll
  for (int r = 0; r < 8; ++r) sm[r] = 0.f;
  for (int it = 0; it < 16; ++it) {
    const int j = it * 256 + tid;
    #pragma unroll
    for (int r = 0; r < 8; ++r) {
      float ev = __expf(slog[r][j] - mx[r]);
      slog[r][j] = ev;
      sm[r] += ev;
    }
  }
  #pragma unroll
  for (int r = 0; r < 8; ++r) {
    #pragma unroll
    for (int off = 32; off > 0; off >>= 1) sm[r] += __shfl_xor(sm[r], off, 64);
  }
  __syncthreads();  // all reads of swred (max) done before reuse
  if (lane == 0) {
    #pragma unroll
    for (int r = 0; r < 8; ++r) swred[wv][r] = sm[r];
  }
  __syncthreads();
  float inv[8];
  #pragma unroll
  for (int r = 0; r < 8; ++r)
    inv[r] = 1.f / (swred[0][r] + swred[1][r] + swred[2][r] + swred[3][r]);

  for (int it = 0; it < 16; ++it) {
    const int j = it * 256 + tid;
    #pragma unroll
    for (int r = 0; r < 8; ++r)
      S[(n0 + r) * 4096 + j] = (bf16)(slog[r][j] * inv[r]);
  }
}

// ---- Xt[b*64+c][m] = bf16(x[b][m][c])  (64x64 fp32 tile via LDS) ----
__global__ __launch_bounds__(256) void xpose_x_k(const float* __restrict__ x, bf16* __restrict__ Xt) {
  __shared__ float tile[64][65];
  const int tid = threadIdx.x;
  const int mt = blockIdx.x, b = blockIdx.y;
  const float* src = x + (b * 4096 + mt * 64) * 64;
  #pragma unroll
  for (int it = 0; it < 16; ++it) {
    const int idx = it * 256 + tid;
    tile[idx >> 6][idx & 63] = src[idx];  // idx = m_local*64 + c, coalesced
  }
  __syncthreads();
  #pragma unroll
  for (int it = 0; it < 16; ++it) {
    const int idx = it * 256 + tid;
    const int rr = idx >> 6, cc = idx & 63;  // rr = c (out row), cc = m_local (out col)
    Xt[(b * 64 + rr) * 4096 + mt * 64 + cc] = (bf16)tile[cc][rr];
  }
}

// ---- bf16 4096x4096 transpose: outT[j][i] = in[i][j]  (fallback if ws too small) ----
__global__ __launch_bounds__(256) void transpose_bf16_k(const bf16* __restrict__ in, bf16* __restrict__ outT) {
  __shared__ bf16 tile[64][65];
  const int tid = threadIdx.x;
  const int ti = blockIdx.x & 63, tj = blockIdx.x >> 6;
  #pragma unroll
  for (int it = 0; it < 16; ++it) {
    const int idx = it * 256 + tid;
    tile[idx >> 6][idx & 63] = in[(ti * 64 + (idx >> 6)) * 4096 + tj * 64 + (idx & 63)];
  }
  __syncthreads();
  #pragma unroll
  for (int it = 0; it < 16; ++it) {
    const int idx = it * 256 + tid;
    const int rr = idx >> 6, cc = idx & 63;
    outT[(tj * 64 + rr) * 4096 + ti * 64 + cc] = tile[cc][rr];
  }
}

// ---- C[n][bc] = A[n][:] . Bt[bc][:]  (4096^3, both operands K-contig row-major) ----
// 128x128 tile, BK=64, 256 threads = 4 waves (2M x 2N), per-wave 64x64 output,
// acc[4][4] f32x4. Round-3 8-region schedule over 2 K-tiles, ONE barrier/region,
// counted vmcnt(6) at R4/R8 only. 64 KiB LDS -> 2 blocks/CU (independent barrier
// gangs overlap each other's stalls). Chunk swizzle: phys16Bchunk(row,c) =
// c ^ ((row>>1)&3) on global source (LDS dst lane-linear) + ds_read offset
// (0 conflicts, round-2 PMC). Optional Ct: transposed C store (for XG1t).
__global__ __launch_bounds__(256, 2) void gemm128_k(const bf16* __restrict__ A,
                                                    const bf16* __restrict__ Bt,
                                                    bf16* __restrict__ C,
                                                    bf16* __restrict__ Ct) {
  __shared__ bf16 As[2][2][128][32];  // [buf][ks][row][k'] : 32 KiB
  __shared__ bf16 Bs[2][2][128][32];  // 32 KiB

  const int tid = threadIdx.x;
  const int bid = blockIdx.x;
  const int wg = (bid & 7) * 128 + (bid >> 3);  // XCD swizzle, 1024 % 8 == 0 -> bijective
  const int tm = wg >> 5, tn = wg & 31;
  const int rowBase = tm * 128, colBase = tn * 128;

  const int wv = tid >> 6, lane = tid & 63;
  const int wm = wv >> 1, wn = wv & 1;
  const int t16 = lane & 15, quad = lane >> 4;
  const int wv16 = wv * 16;
  const int q8 = (quad ^ ((t16 >> 1) & 3)) * 8;  // swizzled phys chunk for ds_read
  const int wm64 = wm * 64;
  const int wn64 = wn * 64;

  // staging: thread t -> row t>>2 (64 rows/load pass); lane writes phys chunk t&3,
  // which holds logical chunk (t&3)^key(row), key = (row>>1)&3 = (t>>3)&3
  // (pass 2 rows are +64: key unchanged since 64/2 = 32 ≡ 0 mod 4)
  const int sr = tid >> 2;
  const int sc = ((tid & 3) ^ ((tid >> 3) & 3)) * 8;
  const bf16* gA = A + (size_t)(rowBase + sr) * 4096 + sc;
  const bf16* gB = Bt + (size_t)(colBase + sr) * 4096 + sc;

  f32x4 acc[4][4];
  #pragma unroll
  for (int i = 0; i < 4; ++i)
    #pragma unroll
    for (int j = 0; j < 4; ++j) acc[i][j] = (f32x4){0.f, 0.f, 0.f, 0.f};

  auto stA = [&](int buf, int s, int k0) {
    async_lds16(gA + k0 + s * 32, &As[buf][s][wv16][0]);
    async_lds16(gA + (size_t)64 * 4096 + k0 + s * 32, &As[buf][s][64 + wv16][0]);
  };
  auto stB = [&](int buf, int s, int k0) {
    async_lds16(gB + k0 + s * 32, &Bs[buf][s][wv16][0]);
    async_lds16(gB + (size_t)64 * 4096 + k0 + s * 32, &Bs[buf][s][64 + wv16][0]);
  };

  bf16x8 Ra[2], Rb[2], B0[4], B1[4];
  auto rdA = [&](bf16x8* R, int buf, int s, int g) {
    #pragma unroll
    for (int i = 0; i < 2; ++i)
      R[i] = *(const bf16x8*)&As[buf][s][wm64 + (g * 2 + i) * 16 + t16][q8];
  };
  auto rdB = [&](bf16x8* R, int buf, int s) {
    #pragma unroll
    for (int j = 0; j < 4; ++j)
      R[j] = *(const bf16x8*)&Bs[buf][s][wn64 + j * 16 + t16][q8];
  };
  auto mfma8 = [&](int g, const bf16x8* R, const bf16x8* Bv) {
    __builtin_amdgcn_s_setprio(1);
    #pragma unroll
    for (int i = 0; i < 2; ++i)
      #pragma unroll
      for (int j = 0; j < 4; ++j)
        acc[g * 2 + i][j] =
            __builtin_amdgcn_mfma_f32_16x16x32_bf16(R[i], Bv[j], acc[g * 2 + i][j], 0, 0, 0);
    __builtin_amdgcn_s_setprio(0);
  };

  // prologue: t0 -> buf0 (4 halves, 8 loads), t1 -> buf1 (3 halves, 6 loads)
  stB(0, 0, 0); stA(0, 0, 0); stB(0, 1, 0); stA(0, 1, 0);
  stB(1, 0, 64); stA(1, 0, 64); stB(1, 1, 64);
  WAIT_VM(6);  // t0 fully landed; t1's 3 halves stay in flight
  BAR();

  for (int it = 0; it < 31; ++it) {
    const int kb = it * 128;
    // R1: buf-switch reads (same-region consume of Ra/B0) + lookahead Rb
    rdA(Ra, 0, 0, 0); rdB(B0, 0, 0); rdA(Rb, 0, 0, 1);
    stA(1, 1, kb + 64);
    mfma8(0, Ra, B0);
    BAR();
    // R2
    rdA(Ra, 0, 1, 0); rdB(B1, 0, 1);
    stB(0, 0, kb + 128);
    mfma8(1, Rb, B0);
    BAR();
    // R3
    rdA(Rb, 0, 1, 1);
    stA(0, 0, kb + 128);
    mfma8(0, Ra, B1);
    BAR();
    // R4: counted wait -> buf1 (t_{2it+1}) fully landed after this barrier
    stB(0, 1, kb + 128);
    mfma8(1, Rb, B1);
    WAIT_VM(6);
    BAR();
    // R5: buf-switch reads of buf1 + lookahead
    rdA(Ra, 1, 0, 0); rdB(B0, 1, 0); rdA(Rb, 1, 0, 1);
    stA(0, 1, kb + 128);
    mfma8(0, Ra, B0);
    BAR();
    // R6
    rdA(Ra, 1, 1, 0); rdB(B1, 1, 1);
    stB(1, 0, kb + 192);
    mfma8(1, Rb, B0);
    BAR();
    // R7
    rdA(Rb, 1, 1, 1);
    stA(1, 0, kb + 192);
    mfma8(0, Ra, B1);
    BAR();
    // R8: counted wait -> buf0 (t_{2it+2}) fully landed after this barrier
    stB(1, 1, kb + 192);
    mfma8(1, Rb, B1);
    WAIT_VM(6);
    BAR();
  }

  // epilogue: tiles 62 (buf0) and 63 (buf1); only remaining stage is t63.Aks1
  rdA(Ra, 0, 0, 0); rdB(B0, 0, 0); rdA(Rb, 0, 0, 1);
  stA(1, 1, 4032);
  mfma8(0, Ra, B0);
  BAR();
  rdA(Ra, 0, 1, 0); rdB(B1, 0, 1);
  mfma8(1, Rb, B0);
  BAR();
  rdA(Rb, 0, 1, 1);
  mfma8(0, Ra, B1);
  BAR();
  mfma8(1, Rb, B1);
  WAIT_VM(0);  // drain: t63 fully landed
  BAR();
  rdA(Ra, 1, 0, 0); rdB(B0, 1, 0); rdA(Rb, 1, 0, 1);
  mfma8(0, Ra, B0);
  rdA(Ra, 1, 1, 0); rdB(B1, 1, 1);
  mfma8(1, Rb, B0);
  rdA(Rb, 1, 1, 1);
  mfma8(0, Ra, B1);
  mfma8(1, Rb, B1);

  // D: row = quad*4+rr (M dim), col = t16 (N dim)
  #pragma unroll
  for (int i = 0; i < 4; ++i) {
    const int row0 = rowBase + wm64 + i * 16 + quad * 4;
    #pragma unroll
    for (int j = 0; j < 4; ++j) {
      const int col = colBase + wn64 + j * 16 + t16;
      #pragma unroll
      for (int rr = 0; rr < 4; ++rr)
        C[(size_t)(row0 + rr) * 4096 + col] = (bf16)acc[i][j][rr];
    }
  }
  if (Ct) {  // transposed store: Ct[col][row], 4 contiguous bf16 (8B) per frag
    #pragma unroll
    for (int i = 0; i < 4; ++i) {
      const int row0 = rowBase + wm64 + i * 16 + quad * 4;
      #pragma unroll
      for (int j = 0; j < 4; ++j) {
        const int col = colBase + wn64 + j * 16 + t16;
        union { bf16 h[4]; uint2 u; } pk;
        #pragma unroll
        for (int rr = 0; rr < 4; ++rr) pk.h[rr] = (bf16)acc[i][j][rr];
        *(uint2*)(Ct + (size_t)col * 4096 + row0) = pk.u;
      }
    }
  }
}

// ---- mix: out[b][n][o] = sum_{kk<192} Acat[n][kk] * Wcat[o][kk] + bias[o]
// LDS-staged (round-6, best measured): x coalesced fp32 -> cvt -> swizzled
// ds_write; XG1/XG2 via global_load_lds (lane-linear dst, pre-swizzled source).
// Chunk-XOR key = row&7. 73 KB LDS -> 2 blocks/CU. One barrier.
__global__ __launch_bounds__(256) void mix_k(const float* __restrict__ x, const bf16* __restrict__ XG1,
                                             const bf16* __restrict__ XG2, const bf16* __restrict__ Wc,
                                             const float* __restrict__ bias, float* __restrict__ out) {
  __shared__ bf16 sW[64 * 200];   // stride 200 (=400B, 16B-aligned rows)
  __shared__ bf16 sX[128 * 64];   // block-local Acat chunks, swizzled
  __shared__ bf16 sG1[128 * 64];
  __shared__ bf16 sG2[128 * 64];
  const int tid = threadIdx.x;
  const int nt = blockIdx.x, b = blockIdx.y;
  const int nBase = nt * 128;
  const int lane = tid & 63, wv = tid >> 6;

  {  // Wc -> sW
    const int rw = tid >> 2, part = tid & 3;
    #pragma unroll
    for (int v = 0; v < 6; ++v)
      *(bf16x8*)(sW + rw * 200 + part * 48 + v * 8) = *(const bf16x8*)(Wc + rw * 192 + part * 48 + v * 8);
  }
  {  // XG1/XG2 -> sG1/sG2: thread t -> row (t>>3)+32p, phys chunk t&7
    const int grow = tid >> 3, gc = tid & 7;
    const int gsrc = (gc ^ (grow & 7)) * 8;
    #pragma unroll
    for (int p = 0; p < 4; ++p) {
      const int r = grow + p * 32;
      async_lds16(XG1 + (size_t)(nBase + r) * 4096 + b * 64 + gsrc, sG1 + p * 2048 + wv * 512);
      async_lds16(XG2 + (size_t)(nBase + r) * 4096 + b * 64 + gsrc, sG2 + p * 2048 + wv * 512);
    }
  }
  {  // x -> sX: thread t, pass p: row=(p*256+t)>>2, seg=t&3 (16 fp32 = 64B, coalesced)
    #pragma unroll
    for (int p = 0; p < 2; ++p) {
      const int idx = p * 256 + tid;
      const int r = idx >> 2, seg = idx & 3;
      const float* px = x + ((size_t)(b * 4096 + nBase + r)) * 64 + seg * 16;
      float4 f0 = *(const float4*)px;
      float4 f1 = *(const float4*)(px + 4);
      float4 f2 = *(const float4*)(px + 8);
      float4 f3 = *(const float4*)(px + 12);
      bf16x8 t0, t1;
      t0[0] = (bf16)f0.x; t0[1] = (bf16)f0.y; t0[2] = (bf16)f0.z; t0[3] = (bf16)f0.w;
      t0[4] = (bf16)f1.x; t0[5] = (bf16)f1.y; t0[6] = (bf16)f1.z; t0[7] = (bf16)f1.w;
      t1[0] = (bf16)f2.x; t1[1] = (bf16)f2.y; t1[2] = (bf16)f2.z; t1[3] = (bf16)f2.w;
      t1[4] = (bf16)f3.x; t1[5] = (bf16)f3.y; t1[6] = (bf16)f3.z; t1[7] = (bf16)f3.w;
      const int key = r & 7, c0 = seg * 2;
      *(bf16x8*)(sX + r * 64 + ((c0) ^ key) * 8) = t0;
      *(bf16x8*)(sX + r * 64 + ((c0 + 1) ^ key) * 8) = t1;
    }
  }
  __syncthreads();  // drains vmcnt (gload_lds) + lgkm (ds_writes)

  const int t16 = lane & 15, quad = lane >> 4;
  const int rloc = wv * 32;

  f32x4 acc[2][4];
  #pragma unroll
  for (int i = 0; i < 2; ++i)
    #pragma unroll
    for (int j = 0; j < 4; ++j) acc[i][j] = (f32x4){0.f, 0.f, 0.f, 0.f};

  #pragma unroll
  for (int ch = 0; ch < 6; ++ch) {
    const bf16* src = (ch < 2) ? sX : (ch < 4) ? sG1 : sG2;
    const int c = (ch & 1) * 4 + quad;
    bf16x8 a[2];
    #pragma unroll
    for (int i = 0; i < 2; ++i) {
      const int r = rloc + i * 16 + t16;
      a[i] = *(const bf16x8*)(src + r * 64 + ((c ^ (r & 7)) * 8));
    }
    #pragma unroll
    for (int j = 0; j < 4; ++j) {
      bf16x8 wf = *(const bf16x8*)(sW + (j * 16 + t16) * 200 + ch * 32 + quad * 8);
      #pragma unroll
      for (int i = 0; i < 2; ++i)
        acc[i][j] = __builtin_amdgcn_mfma_f32_16x16x32_bf16(a[i], wf, acc[i][j], 0, 0, 0);
    }
  }

  #pragma unroll
  for (int j = 0; j < 4; ++j) {
    const float bb = bias[j * 16 + t16];
    #pragma unroll
    for (int i = 0; i < 2; ++i) {
      const int n0 = nBase + wv * 32 + i * 16 + quad * 4;
      #pragma unroll
      for (int rr = 0; rr < 4; ++rr)
        out[(b * 4096 + n0 + rr) * 64 + j * 16 + t16] = acc[i][j][rr] + bb;
    }
  }
}

extern "C" void kernel_launch(void* const* d_in, const int* in_sizes, int n_in,
                              void* d_out, int out_size, void* d_ws, size_t ws_size,
                              hipStream_t stream) {
  const float* x    = (const float*)d_in[0];  // [64,4096,64]
  const float* adj  = (const float*)d_in[1];  // [4096,16]
  const float* emb  = (const float*)d_in[2];  // [16,4096]
  const float* w    = (const float*)d_in[3];  // [3,64,64]
  const float* bias = (const float*)d_in[4];  // [64]
  float* out = (float*)d_out;

  char* ws = (char*)d_ws;
  const size_t SZ = (size_t)4096 * 4096 * sizeof(bf16);  // 32 MiB
  bf16* S    = (bf16*)(ws);            // [n][m]
  bf16* XG1  = (bf16*)(ws + SZ);       // [n][bc]
  bf16* XG2  = (bf16*)(ws + 2 * SZ);   // [n][bc]
  bf16* XBUF = (bf16*)(ws + 3 * SZ);   // Xt [bc][m] (and XG1t fallback)
  const bool fused_t = ws_size >= 5 * SZ + (size_t)(64 * 192 * sizeof(bf16));
  bf16* XG1T = fused_t ? (bf16*)(ws + 4 * SZ) : XBUF;  // [bc][m]
  bf16* Wc   = (bf16*)(ws + (fused_t ? 5 : 4) * SZ);   // [64][192]

  supports_k<<<512, 256, 0, stream>>>(adj, emb, S, w, Wc);  // + fused wcat
  xpose_x_k<<<dim3(64, 64), 256, 0, stream>>>(x, XBUF);
  gemm128_k<<<1024, 256, 0, stream>>>(S, XBUF, XG1, fused_t ? XG1T : nullptr);
  if (!fused_t) transpose_bf16_k<<<4096, 256, 0, stream>>>(XG1, XBUF);  // XG1t
  gemm128_k<<<1024, 256, 0, stream>>>(S, XG1T, XG2, nullptr);           // XG2 = S @ XG1
  mix_k<<<dim3(32, 64), 256, 0, stream>>>(x, XG1, XG2, Wc, bias, out);
}

// Round 9
// 428.857 us; speedup vs baseline: 1.2381x; 1.2381x over previous
//
#include <hip/hip_runtime.h>

// AVWGCN: out[b,n,o] = sum_k sum_i xg_k[b,n,i] * w[k,i,o] + bias[o]
//   xg0 = x, xg1 = S@x, xg2 = 2*S@(S@x) - x   (S = softmax(relu(adj@emb), rows))
// Algebra: never form T2; fold "2*" and "-x" into Wcat = [w0-w2 | w1 | 2*w2].
// GEMM: 256x256 tile, BK=64, **1024 threads = 16 waves (4Mx4N)**, 64x64/wave.
// Same traffic as the 137-µs 8-wave version (round-8's 128² regression was
// FETCH-doubling, not gang structure) but 4 waves/SIMD instead of 2 — the
// occupancy axis, isolated. Round-3 8-region single-barrier schedule, counted
// vmcnt(3) (1 load/thread/half). Chunk-XOR swizzle (0 conflicts, round-2 PMC).
// Stage-safety re-derived: every overwritten half's reads lgkm-drain >=1
// barrier before its re-stage (all 8 sites walked).

typedef __bf16 bf16;
typedef __bf16 bf16x8 __attribute__((ext_vector_type(8)));
typedef float f32x4 __attribute__((ext_vector_type(4)));

__device__ __forceinline__ void async_lds16(const void* g, void* l) {
  __builtin_amdgcn_global_load_lds((const __attribute__((address_space(1))) void*)g,
                                   (__attribute__((address_space(3))) void*)l, 16, 0, 0);
}

#define FENCE() asm volatile("" ::: "memory")
#define BAR()                          \
  do {                                 \
    FENCE();                           \
    __builtin_amdgcn_s_barrier();      \
    FENCE();                           \
  } while (0)
#define WAIT_VM(n) asm volatile("s_waitcnt vmcnt(" #n ")" ::: "memory")

// ---- S rows softmax(relu(adj@emb)) + (blocks 0..47) Wcat build fused ----
__global__ __launch_bounds__(256) void supports_k(const float* __restrict__ adj,
                                                  const float* __restrict__ emb,
                                                  bf16* __restrict__ S,
                                                  const float* __restrict__ w,
                                                  bf16* __restrict__ Wc) {
  const int tid = threadIdx.x;
  {  // fused wcat: 64*192 = 12288 elems over blocks 0..47
    const int idx = blockIdx.x * 256 + tid;
    if (idx < 64 * 192) {
      const int o = idx / 192, kk = idx - o * 192;
      const int k = kk >> 6, i = kk & 63;
      float v;
      if (k == 0)      v = w[i * 64 + o] - w[2 * 4096 + i * 64 + o];
      else if (k == 1) v = w[4096 + i * 64 + o];
      else             v = 2.f * w[2 * 4096 + i * 64 + o];
      Wc[idx] = (bf16)v;
    }
  }
  __shared__ float slog[8][4096];  // 128 KiB logit stash
  __shared__ float sadj[8][16];
  __shared__ float swred[4][8];
  const int lane = tid & 63, wv = tid >> 6;
  const int n0 = blockIdx.x * 8;
  if (tid < 128) sadj[tid >> 4][tid & 15] = adj[n0 * 16 + tid];
  __syncthreads();

  float mx[8];
  #pragma unroll
  for (int r = 0; r < 8; ++r) mx[r] = 0.f;  // relu => max >= 0

  for (int it = 0; it < 16; ++it) {
    const int j = it * 256 + tid;
    float e[16];
    #pragma unroll
    for (int k = 0; k < 16; ++k) e[k] = emb[k * 4096 + j];
    #pragma unroll
    for (int r = 0; r < 8; ++r) {
      float v = 0.f;
      #pragma unroll
      for (int k = 0; k < 16; ++k) v = fmaf(sadj[r][k], e[k], v);
      v = fmaxf(v, 0.f);
      slog[r][j] = v;
      mx[r] = fmaxf(mx[r], v);
    }
  }
  #pragma unroll
  for (int r = 0; r < 8; ++r) {
    #pragma unroll
    for (int off = 32; off > 0; off >>= 1) mx[r] = fmaxf(mx[r], __shfl_xor(mx[r], off, 64));
  }
  if (lane == 0) {
    #pragma unroll
    for (int r = 0; r < 8; ++r) swred[wv][r] = mx[r];
  }
  __syncthreads();
  #pragma unroll
  for (int r = 0; r < 8; ++r)
    mx[r] = fmaxf(fmaxf(swred[0][r], swred[1][r]), fmaxf(swred[2][r], swred[3][r]));

  float sm[8];
  #pragma unroll
  for (int r = 0; r < 8; ++r) sm[r] = 0.f;
  for (int it = 0; it < 16; ++it) {
    const int j = it * 256 + tid;
    #pragma unroll
    for (int r = 0; r < 8; ++r) {
      float ev = __expf(slog[r][j] - mx[r]);
      slog[r][j] = ev;
      sm[r] += ev;
    }
  }
  #pragma unroll
  for (int r = 0; r < 8; ++r) {
    #pragma unroll
    for (int off = 32; off > 0; off >>= 1) sm[r] += __shfl_xor(sm[r], off, 64);
  }
  __syncthreads();  // all reads of swred (max) done before reuse
  if (lane == 0) {
    #pragma unroll
    for (int r = 0; r < 8; ++r) swred[wv][r] = sm[r];
  }
  __syncthreads();
  float inv[8];
  #pragma unroll
  for (int r = 0; r < 8; ++r)
    inv[r] = 1.f / (swred[0][r] + swred[1][r] + swred[2][r] + swred[3][r]);

  for (int it = 0; it < 16; ++it) {
    const int j = it * 256 + tid;
    #pragma unroll
    for (int r = 0; r < 8; ++r)
      S[(n0 + r) * 4096 + j] = (bf16)(slog[r][j] * inv[r]);
  }
}

// ---- Xt[b*64+c][m] = bf16(x[b][m][c])  (64x64 fp32 tile via LDS) ----
__global__ __launch_bounds__(256) void xpose_x_k(const float* __restrict__ x, bf16* __restrict__ Xt) {
  __shared__ float tile[64][65];
  const int tid = threadIdx.x;
  const int mt = blockIdx.x, b = blockIdx.y;
  const float* src = x + (b * 4096 + mt * 64) * 64;
  #pragma unroll
  for (int it = 0; it < 16; ++it) {
    const int idx = it * 256 + tid;
    tile[idx >> 6][idx & 63] = src[idx];  // idx = m_local*64 + c, coalesced
  }
  __syncthreads();
  #pragma unroll
  for (int it = 0; it < 16; ++it) {
    const int idx = it * 256 + tid;
    const int rr = idx >> 6, cc = idx & 63;  // rr = c (out row), cc = m_local (out col)
    Xt[(b * 64 + rr) * 4096 + mt * 64 + cc] = (bf16)tile[cc][rr];
  }
}

// ---- bf16 4096x4096 transpose: outT[j][i] = in[i][j]  (fallback if ws too small) ----
__global__ __launch_bounds__(256) void transpose_bf16_k(const bf16* __restrict__ in, bf16* __restrict__ outT) {
  __shared__ bf16 tile[64][65];
  const int tid = threadIdx.x;
  const int ti = blockIdx.x & 63, tj = blockIdx.x >> 6;
  #pragma unroll
  for (int it = 0; it < 16; ++it) {
    const int idx = it * 256 + tid;
    tile[idx >> 6][idx & 63] = in[(ti * 64 + (idx >> 6)) * 4096 + tj * 64 + (idx & 63)];
  }
  __syncthreads();
  #pragma unroll
  for (int it = 0; it < 16; ++it) {
    const int idx = it * 256 + tid;
    const int rr = idx >> 6, cc = idx & 63;
    outT[(tj * 64 + rr) * 4096 + ti * 64 + cc] = tile[cc][rr];
  }
}

// ---- C[n][bc] = A[n][:] . Bt[bc][:]  (4096^3) — 1024-thread 256² tile ----
// 16 waves (4Mx4N), 64x64/wave, acc[4][4]. 8 regions / 2 K-tiles, one barrier
// each. Region: { ds_reads | stage 1 half (1 gload_lds/thread) | mfma8 |
// [R4/R8: WAIT_VM(3)] | BAR }. Stage order: R1 t+1.Bs1 | R2 t+2.As0 |
// R3 t+2.Bs0 | R4 t+2.As1 | R5 t+2.Bs1 | R6 t+3.As0 | R7 t+3.Bs0 | R8 t+3.As1.
// Safety: each overwritten half's reads are consumed (lgkm-drained) >=1 barrier
// before its stage. vmcnt(3)@R4: t+1's last half (R1) landed before buf1 reads
// at R5; vmcnt(3)@R8: t+2's last half (R5) landed before buf0 reads at next R1.
__global__ __launch_bounds__(1024) void gemm256w16_k(const bf16* __restrict__ A,
                                                     const bf16* __restrict__ Bt,
                                                     bf16* __restrict__ C,
                                                     bf16* __restrict__ Ct) {
  __shared__ bf16 As[2][2][256][32];  // [buf][ks][row][k'] : 64 KiB
  __shared__ bf16 Bs[2][2][256][32];  // 64 KiB

  const int tid = threadIdx.x;
  const int bid = blockIdx.x;
  const int wg = (bid & 7) * 32 + (bid >> 3);  // XCD swizzle, 256 % 8 == 0 -> bijective
  const int tm = wg >> 4, tn = wg & 15;
  const int rowBase = tm * 256, colBase = tn * 256;

  const int wv = tid >> 6, lane = tid & 63;
  const int wm = wv >> 2, wn = wv & 3;        // 4x4 waves
  const int t16 = lane & 15, quad = lane >> 4;
  const int wv16 = wv * 16;
  const int q8 = (quad ^ ((t16 >> 1) & 3)) * 8;  // swizzled phys chunk for ds_read
  const int wm64 = wm * 64;
  const int wn64 = wn * 64;

  // staging: thread t -> row t>>2 (256 rows in one pass); phys chunk t&3 holds
  // logical chunk (t&3)^key(row), key = (row>>1)&3 = (t>>3)&3; dst lane-linear.
  const int sr = tid >> 2;
  const int sc = ((tid & 3) ^ ((tid >> 3) & 3)) * 8;
  const bf16* gA = A + (size_t)(rowBase + sr) * 4096 + sc;
  const bf16* gB = Bt + (size_t)(colBase + sr) * 4096 + sc;

  f32x4 acc[4][4];
  #pragma unroll
  for (int i = 0; i < 4; ++i)
    #pragma unroll
    for (int j = 0; j < 4; ++j) acc[i][j] = (f32x4){0.f, 0.f, 0.f, 0.f};

  auto stA = [&](int buf, int s, int k0) {
    async_lds16(gA + k0 + s * 32, &As[buf][s][wv16][0]);  // 1 load: 16 KB via 16 waves
  };
  auto stB = [&](int buf, int s, int k0) {
    async_lds16(gB + k0 + s * 32, &Bs[buf][s][wv16][0]);
  };

  bf16x8 Ra[4], Rb[4], B0[2], B1[2];
  auto rdA = [&](bf16x8* R, int buf, int s) {
    #pragma unroll
    for (int i = 0; i < 4; ++i)
      R[i] = *(const bf16x8*)&As[buf][s][wm64 + i * 16 + t16][q8];
  };
  auto rdB2 = [&](bf16x8* R, int buf, int s, int h) {
    #pragma unroll
    for (int j = 0; j < 2; ++j)
      R[j] = *(const bf16x8*)&Bs[buf][s][wn64 + (h * 2 + j) * 16 + t16][q8];
  };
  auto mfma8 = [&](const bf16x8* Av, const bf16x8* Bp, int h) {
    __builtin_amdgcn_s_setprio(1);
    #pragma unroll
    for (int i = 0; i < 4; ++i)
      #pragma unroll
      for (int j = 0; j < 2; ++j)
        acc[i][h * 2 + j] =
            __builtin_amdgcn_mfma_f32_16x16x32_bf16(Av[i], Bp[j], acc[i][h * 2 + j], 0, 0, 0);
    __builtin_amdgcn_s_setprio(0);
  };

  // prologue: t0 -> buf0 (4 halves), t1 -> buf1 (3 halves; Bs1 staged at first R1)
  stA(0, 0, 0); stB(0, 0, 0); stA(0, 1, 0); stB(0, 1, 0);
  stA(1, 0, 64); stB(1, 0, 64); stA(1, 1, 64);
  WAIT_VM(3);  // t0's 4 halves landed; t1's 3 stay in flight
  BAR();

  for (int it = 0; it < 31; ++it) {
    const int kb = it * 128;
    // R1: buf0 ks0 — same-region reads (drained by this region's mfma)
    rdA(Ra, 0, 0); rdB2(B0, 0, 0, 0); rdB2(B1, 0, 0, 1);
    stB(1, 1, kb + 64);   // t+1.Bs1 (old: read prev R7, drained prev bar R7/R8)
    mfma8(Ra, B0, 0);
    BAR();
    // R2
    rdA(Rb, 0, 1);
    stA(0, 0, kb + 128);  // t+2.As0 (old Ra: drained bar R1)
    mfma8(Ra, B1, 1);
    BAR();
    // R3
    rdB2(B0, 0, 1, 0); rdB2(B1, 0, 1, 1);
    stB(0, 0, kb + 128);  // t+2.Bs0 (old B0 bar R1, old B1 bar R2)
    mfma8(Rb, B0, 0);
    BAR();
    // R4
    stA(0, 1, kb + 128);  // t+2.As1 (Rb drained bar R3)
    mfma8(Rb, B1, 1);
    WAIT_VM(3);           // t+1 fully landed (R1's stage); buf1 read after barrier
    BAR();
    // R5: buf1 ks0
    rdA(Ra, 1, 0); rdB2(B0, 1, 0, 0); rdB2(B1, 1, 0, 1);
    stB(0, 1, kb + 128);  // t+2.Bs1 (B0 bar R3, B1 bar R4)
    mfma8(Ra, B0, 0);
    BAR();
    // R6
    rdA(Rb, 1, 1);
    stA(1, 0, kb + 192);  // t+3.As0 (Ra drained bar R5)
    mfma8(Ra, B1, 1);
    BAR();
    // R7
    rdB2(B0, 1, 1, 0); rdB2(B1, 1, 1, 1);
    stB(1, 0, kb + 192);  // t+3.Bs0 (B0 bar R5, B1 bar R6)
    mfma8(Rb, B0, 0);
    BAR();
    // R8
    stA(1, 1, kb + 192);  // t+3.As1 (Rb drained bar R7)
    mfma8(Rb, B1, 1);
    WAIT_VM(3);           // t+2 fully landed (R5's stage); buf0 read next R1
    BAR();
  }

  // epilogue: tiles 62 (buf0) and 63 (buf1); only remaining stage is t63.Bs1
  rdA(Ra, 0, 0); rdB2(B0, 0, 0, 0); rdB2(B1, 0, 0, 1);
  stB(1, 1, 4032);
  mfma8(Ra, B0, 0);
  BAR();
  rdA(Rb, 0, 1);
  mfma8(Ra, B1, 1);
  BAR();
  rdB2(B0, 0, 1, 0); rdB2(B1, 0, 1, 1);
  mfma8(Rb, B0, 0);
  BAR();
  mfma8(Rb, B1, 1);
  WAIT_VM(0);  // t63 fully landed
  BAR();
  rdA(Ra, 1, 0); rdB2(B0, 1, 0, 0); rdB2(B1, 1, 0, 1);
  mfma8(Ra, B0, 0);
  rdA(Rb, 1, 1);
  mfma8(Ra, B1, 1);
  rdB2(B0, 1, 1, 0); rdB2(B1, 1, 1, 1);
  mfma8(Rb, B0, 0);
  mfma8(Rb, B1, 1);

  // D: row = quad*4+rr (M dim), col = t16 (N dim)
  #pragma unroll
  for (int i = 0; i < 4; ++i) {
    const int row0 = rowBase + wm64 + i * 16 + quad * 4;
    #pragma unroll
    for (int j = 0; j < 4; ++j) {
      const int col = colBase + wn64 + j * 16 + t16;
      #pragma unroll
      for (int rr = 0; rr < 4; ++rr)
        C[(size_t)(row0 + rr) * 4096 + col] = (bf16)acc[i][j][rr];
    }
  }
  if (Ct) {  // transposed store: Ct[col][row], 4 contiguous bf16 (8B) per frag
    #pragma unroll
    for (int i = 0; i < 4; ++i) {
      const int row0 = rowBase + wm64 + i * 16 + quad * 4;
      #pragma unroll
      for (int j = 0; j < 4; ++j) {
        const int col = colBase + wn64 + j * 16 + t16;
        union { bf16 h[4]; uint2 u; } pk;
        #pragma unroll
        for (int rr = 0; rr < 4; ++rr) pk.h[rr] = (bf16)acc[i][j][rr];
        *(uint2*)(Ct + (size_t)col * 4096 + row0) = pk.u;
      }
    }
  }
}

// ---- mix: out[b][n][o] = sum_{kk<192} Acat[n][kk] * Wcat[o][kk] + bias[o]
// Round-6 LDS-staged version (best measured).
__global__ __launch_bounds__(256) void mix_k(const float* __restrict__ x, const bf16* __restrict__ XG1,
                                             const bf16* __restrict__ XG2, const bf16* __restrict__ Wc,
                                             const float* __restrict__ bias, float* __restrict__ out) {
  __shared__ bf16 sW[64 * 200];   // stride 200 (=400B, 16B-aligned rows)
  __shared__ bf16 sX[128 * 64];   // block-local Acat chunks, swizzled
  __shared__ bf16 sG1[128 * 64];
  __shared__ bf16 sG2[128 * 64];
  const int tid = threadIdx.x;
  const int nt = blockIdx.x, b = blockIdx.y;
  const int nBase = nt * 128;
  const int lane = tid & 63, wv = tid >> 6;

  {  // Wc -> sW
    const int rw = tid >> 2, part = tid & 3;
    #pragma unroll
    for (int v = 0; v < 6; ++v)
      *(bf16x8*)(sW + rw * 200 + part * 48 + v * 8) = *(const bf16x8*)(Wc + rw * 192 + part * 48 + v * 8);
  }
  {  // XG1/XG2 -> sG1/sG2
    const int grow = tid >> 3, gc = tid & 7;
    const int gsrc = (gc ^ (grow & 7)) * 8;
    #pragma unroll
    for (int p = 0; p < 4; ++p) {
      const int r = grow + p * 32;
      async_lds16(XG1 + (size_t)(nBase + r) * 4096 + b * 64 + gsrc, sG1 + p * 2048 + wv * 512);
      async_lds16(XG2 + (size_t)(nBase + r) * 4096 + b * 64 + gsrc, sG2 + p * 2048 + wv * 512);
    }
  }
  {  // x -> sX coalesced + cvt + swizzled ds_write
    #pragma unroll
    for (int p = 0; p < 2; ++p) {
      const int idx = p * 256 + tid;
      const int r = idx >> 2, seg = idx & 3;
      const float* px = x + ((size_t)(b * 4096 + nBase + r)) * 64 + seg * 16;
      float4 f0 = *(const float4*)px;
      float4 f1 = *(const float4*)(px + 4);
      float4 f2 = *(const float4*)(px + 8);
      float4 f3 = *(const float4*)(px + 12);
      bf16x8 t0, t1;
      t0[0] = (bf16)f0.x; t0[1] = (bf16)f0.y; t0[2] = (bf16)f0.z; t0[3] = (bf16)f0.w;
      t0[4] = (bf16)f1.x; t0[5] = (bf16)f1.y; t0[6] = (bf16)f1.z; t0[7] = (bf16)f1.w;
      t1[0] = (bf16)f2.x; t1[1] = (bf16)f2.y; t1[2] = (bf16)f2.z; t1[3] = (bf16)f2.w;
      t1[4] = (bf16)f3.x; t1[5] = (bf16)f3.y; t1[6] = (bf16)f3.z; t1[7] = (bf16)f3.w;
      const int key = r & 7, c0 = seg * 2;
      *(bf16x8*)(sX + r * 64 + ((c0) ^ key) * 8) = t0;
      *(bf16x8*)(sX + r * 64 + ((c0 + 1) ^ key) * 8) = t1;
    }
  }
  __syncthreads();  // drains vmcnt (gload_lds) + lgkm (ds_writes)

  const int t16 = lane & 15, quad = lane >> 4;
  const int rloc = wv * 32;

  f32x4 acc[2][4];
  #pragma unroll
  for (int i = 0; i < 2; ++i)
    #pragma unroll
    for (int j = 0; j < 4; ++j) acc[i][j] = (f32x4){0.f, 0.f, 0.f, 0.f};

  #pragma unroll
  for (int ch = 0; ch < 6; ++ch) {
    const bf16* src = (ch < 2) ? sX : (ch < 4) ? sG1 : sG2;
    const int c = (ch & 1) * 4 + quad;
    bf16x8 a[2];
    #pragma unroll
    for (int i = 0; i < 2; ++i) {
      const int r = rloc + i * 16 + t16;
      a[i] = *(const bf16x8*)(src + r * 64 + ((c ^ (r & 7)) * 8));
    }
    #pragma unroll
    for (int j = 0; j < 4; ++j) {
      bf16x8 wf = *(const bf16x8*)(sW + (j * 16 + t16) * 200 + ch * 32 + quad * 8);
      #pragma unroll
      for (int i = 0; i < 2; ++i)
        acc[i][j] = __builtin_amdgcn_mfma_f32_16x16x32_bf16(a[i], wf, acc[i][j], 0, 0, 0);
    }
  }

  #pragma unroll
  for (int j = 0; j < 4; ++j) {
    const float bb = bias[j * 16 + t16];
    #pragma unroll
    for (int i = 0; i < 2; ++i) {
      const int n0 = nBase + wv * 32 + i * 16 + quad * 4;
      #pragma unroll
      for (int rr = 0; rr < 4; ++rr)
        out[(b * 4096 + n0 + rr) * 64 + j * 16 + t16] = acc[i][j][rr] + bb;
    }
  }
}

extern "C" void kernel_launch(void* const* d_in, const int* in_sizes, int n_in,
                              void* d_out, int out_size, void* d_ws, size_t ws_size,
                              hipStream_t stream) {
  const float* x    = (const float*)d_in[0];  // [64,4096,64]
  const float* adj  = (const float*)d_in[1];  // [4096,16]
  const float* emb  = (const float*)d_in[2];  // [16,4096]
  const float* w    = (const float*)d_in[3];  // [3,64,64]
  const float* bias = (const float*)d_in[4];  // [64]
  float* out = (float*)d_out;

  char* ws = (char*)d_ws;
  const size_t SZ = (size_t)4096 * 4096 * sizeof(bf16);  // 32 MiB
  bf16* S    = (bf16*)(ws);            // [n][m]
  bf16* XG1  = (bf16*)(ws + SZ);       // [n][bc]
  bf16* XG2  = (bf16*)(ws + 2 * SZ);   // [n][bc]
  bf16* XBUF = (bf16*)(ws + 3 * SZ);   // Xt [bc][m] (and XG1t fallback)
  const bool fused_t = ws_size >= 5 * SZ + (size_t)(64 * 192 * sizeof(bf16));
  bf16* XG1T = fused_t ? (bf16*)(ws + 4 * SZ) : XBUF;  // [bc][m]
  bf16* Wc   = (bf16*)(ws + (fused_t ? 5 : 4) * SZ);   // [64][192]

  supports_k<<<512, 256, 0, stream>>>(adj, emb, S, w, Wc);  // + fused wcat
  xpose_x_k<<<dim3(64, 64), 256, 0, stream>>>(x, XBUF);
  gemm256w16_k<<<256, 1024, 0, stream>>>(S, XBUF, XG1, fused_t ? XG1T : nullptr);
  if (!fused_t) transpose_bf16_k<<<4096, 256, 0, stream>>>(XG1, XBUF);  // XG1t
  gemm256w16_k<<<256, 1024, 0, stream>>>(S, XG1T, XG2, nullptr);        // XG2 = S @ XG1
  mix_k<<<dim3(32, 64), 256, 0, stream>>>(x, XG1, XG2, Wc, bias, out);
}

// Round 10
// 419.888 us; speedup vs baseline: 1.2646x; 1.0214x over previous
//
#include <hip/hip_runtime.h>

// AVWGCN: out[b,n,o] = sum_k sum_i xg_k[b,n,i] * w[k,i,o] + bias[o]
//   xg0 = x, xg1 = S@x, xg2 = 2*S@(S@x) - x   (S = softmax(relu(adj@emb), rows))
// Algebra: never form T2; fold "2*" and "-x" into Wcat = [w0-w2 | w1 | 2*w2].
// GEMM: round-9 best — 256x256 tile, BK=64, 16 waves (4Mx4N), 8-region
// counted-vmcnt schedule, chunk-XOR swizzle (124 µs, MfmaUtil 50%, 0 conflicts).
// This round: pre_k fuses {supports (64KB slog, 2 halves -> 2 blk/CU, was 1) +
// wcat + xpose} into one launch; supports blocks dispatch first so their
// latency-bound tail overlaps xpose's BW-bound blocks.

typedef __bf16 bf16;
typedef __bf16 bf16x8 __attribute__((ext_vector_type(8)));
typedef float f32x4 __attribute__((ext_vector_type(4)));

__device__ __forceinline__ void async_lds16(const void* g, void* l) {
  __builtin_amdgcn_global_load_lds((const __attribute__((address_space(1))) void*)g,
                                   (__attribute__((address_space(3))) void*)l, 16, 0, 0);
}

#define FENCE() asm volatile("" ::: "memory")
#define BAR()                          \
  do {                                 \
    FENCE();                           \
    __builtin_amdgcn_s_barrier();      \
    FENCE();                           \
  } while (0)
#define WAIT_VM(n) asm volatile("s_waitcnt vmcnt(" #n ")" ::: "memory")

// ---- pre_k: blocks 0..511 = supports rows (8/block, two 4-row halves) + wcat
//      (blocks 0..47); blocks 512..4607 = x transpose tiles. LDS union 66 KB
//      -> 2 blocks/CU for both paths (supports was 1 blk/CU at 128 KB). ----
__global__ __launch_bounds__(256) void pre_k(const float* __restrict__ adj,
                                             const float* __restrict__ emb,
                                             bf16* __restrict__ S,
                                             const float* __restrict__ w,
                                             bf16* __restrict__ Wc,
                                             const float* __restrict__ x,
                                             bf16* __restrict__ Xt) {
  __shared__ float smem[4 * 4096 + 160];  // slog[4][4096] | sadj[8][16] | swred[4][4]
  const int tid = threadIdx.x;
  const int bidx = blockIdx.x;

  if (bidx >= 512) {  // ---- xpose path ----
    float(*tile)[65] = (float(*)[65])smem;  // 64*65 = 4160 floats, fits slog region
    const int bid2 = bidx - 512;
    const int mt = bid2 & 63, b = bid2 >> 6;
    const float* src = x + (b * 4096 + mt * 64) * 64;
    #pragma unroll
    for (int it = 0; it < 16; ++it) {
      const int idx = it * 256 + tid;
      tile[idx >> 6][idx & 63] = src[idx];  // idx = m_local*64 + c, coalesced
    }
    __syncthreads();
    #pragma unroll
    for (int it = 0; it < 16; ++it) {
      const int idx = it * 256 + tid;
      const int rr = idx >> 6, cc = idx & 63;  // rr = c (out row), cc = m_local
      Xt[(b * 64 + rr) * 4096 + mt * 64 + cc] = (bf16)tile[cc][rr];
    }
    return;
  }

  // ---- supports path ----
  float* slog = smem;                  // [4][4096]
  float* sadj = smem + 16384;          // [8][16]
  float* swred = smem + 16384 + 128;   // [4][4]
  const int lane = tid & 63, wv = tid >> 6;
  const int n0 = bidx * 8;
  {  // fused wcat: 64*192 = 12288 elems over blocks 0..47
    const int idx = bidx * 256 + tid;
    if (idx < 64 * 192) {
      const int o = idx / 192, kk = idx - o * 192;
      const int k = kk >> 6, i = kk & 63;
      float v;
      if (k == 0)      v = w[i * 64 + o] - w[2 * 4096 + i * 64 + o];
      else if (k == 1) v = w[4096 + i * 64 + o];
      else             v = 2.f * w[2 * 4096 + i * 64 + o];
      Wc[idx] = (bf16)v;
    }
  }
  if (tid < 128) sadj[tid] = adj[n0 * 16 + tid];
  __syncthreads();

  for (int h = 0; h < 2; ++h) {  // rows h*4 .. h*4+3
    const float* sa = sadj + h * 64;
    float mx[4];
    #pragma unroll
    for (int r = 0; r < 4; ++r) mx[r] = 0.f;  // relu => max >= 0

    for (int it = 0; it < 16; ++it) {
      const int j = it * 256 + tid;
      float e[16];
      #pragma unroll
      for (int k = 0; k < 16; ++k) e[k] = emb[k * 4096 + j];
      #pragma unroll
      for (int r = 0; r < 4; ++r) {
        float v = 0.f;
        #pragma unroll
        for (int k = 0; k < 16; ++k) v = fmaf(sa[r * 16 + k], e[k], v);
        v = fmaxf(v, 0.f);
        slog[r * 4096 + j] = v;
        mx[r] = fmaxf(mx[r], v);
      }
    }
    #pragma unroll
    for (int r = 0; r < 4; ++r) {
      #pragma unroll
      for (int off = 32; off > 0; off >>= 1) mx[r] = fmaxf(mx[r], __shfl_xor(mx[r], off, 64));
    }
    if (lane == 0) {
      #pragma unroll
      for (int r = 0; r < 4; ++r) swred[wv * 4 + r] = mx[r];
    }
    __syncthreads();
    #pragma unroll
    for (int r = 0; r < 4; ++r)
      mx[r] = fmaxf(fmaxf(swred[0 + r], swred[4 + r]), fmaxf(swred[8 + r], swred[12 + r]));

    float sm[4];
    #pragma unroll
    for (int r = 0; r < 4; ++r) sm[r] = 0.f;
    for (int it = 0; it < 16; ++it) {
      const int j = it * 256 + tid;
      #pragma unroll
      for (int r = 0; r < 4; ++r) {
        float ev = __expf(slog[r * 4096 + j] - mx[r]);
        slog[r * 4096 + j] = ev;
        sm[r] += ev;
      }
    }
    #pragma unroll
    for (int r = 0; r < 4; ++r) {
      #pragma unroll
      for (int off = 32; off > 0; off >>= 1) sm[r] += __shfl_xor(sm[r], off, 64);
    }
    __syncthreads();  // all reads of swred (max) done before reuse
    if (lane == 0) {
      #pragma unroll
      for (int r = 0; r < 4; ++r) swred[wv * 4 + r] = sm[r];
    }
    __syncthreads();
    float inv[4];
    #pragma unroll
    for (int r = 0; r < 4; ++r)
      inv[r] = 1.f / (swred[0 + r] + swred[4 + r] + swred[8 + r] + swred[12 + r]);

    for (int it = 0; it < 16; ++it) {
      const int j = it * 256 + tid;
      #pragma unroll
      for (int r = 0; r < 4; ++r)
        S[(n0 + h * 4 + r) * 4096 + j] = (bf16)(slog[r * 4096 + j] * inv[r]);
    }
    __syncthreads();  // slog/swred reuse next half
  }
}

// ---- bf16 4096x4096 transpose: outT[j][i] = in[i][j]  (fallback if ws too small) ----
__global__ __launch_bounds__(256) void transpose_bf16_k(const bf16* __restrict__ in, bf16* __restrict__ outT) {
  __shared__ bf16 tile[64][65];
  const int tid = threadIdx.x;
  const int ti = blockIdx.x & 63, tj = blockIdx.x >> 6;
  #pragma unroll
  for (int it = 0; it < 16; ++it) {
    const int idx = it * 256 + tid;
    tile[idx >> 6][idx & 63] = in[(ti * 64 + (idx >> 6)) * 4096 + tj * 64 + (idx & 63)];
  }
  __syncthreads();
  #pragma unroll
  for (int it = 0; it < 16; ++it) {
    const int idx = it * 256 + tid;
    const int rr = idx >> 6, cc = idx & 63;
    outT[(tj * 64 + rr) * 4096 + ti * 64 + cc] = tile[cc][rr];
  }
}

// ---- C[n][bc] = A[n][:] . Bt[bc][:]  (4096^3) — 1024-thread 256² tile ----
// 16 waves (4Mx4N), 64x64/wave, acc[4][4]. 8 regions / 2 K-tiles, one barrier
// each. Region: { ds_reads | stage 1 half (1 gload_lds/thread) | mfma8 |
// [R4/R8: WAIT_VM(3)] | BAR }. Stage order: R1 t+1.Bs1 | R2 t+2.As0 |
// R3 t+2.Bs0 | R4 t+2.As1 | R5 t+2.Bs1 | R6 t+3.As0 | R7 t+3.Bs0 | R8 t+3.As1.
// Safety: each overwritten half's reads are consumed (lgkm-drained) >=1 barrier
// before its stage. vmcnt(3)@R4: t+1's last half (R1) landed before buf1 reads
// at R5; vmcnt(3)@R8: t+2's last half (R5) landed before buf0 reads at next R1.
__global__ __launch_bounds__(1024) void gemm256w16_k(const bf16* __restrict__ A,
                                                     const bf16* __restrict__ Bt,
                                                     bf16* __restrict__ C,
                                                     bf16* __restrict__ Ct) {
  __shared__ bf16 As[2][2][256][32];  // [buf][ks][row][k'] : 64 KiB
  __shared__ bf16 Bs[2][2][256][32];  // 64 KiB

  const int tid = threadIdx.x;
  const int bid = blockIdx.x;
  const int wg = (bid & 7) * 32 + (bid >> 3);  // XCD swizzle, 256 % 8 == 0 -> bijective
  const int tm = wg >> 4, tn = wg & 15;
  const int rowBase = tm * 256, colBase = tn * 256;

  const int wv = tid >> 6, lane = tid & 63;
  const int wm = wv >> 2, wn = wv & 3;        // 4x4 waves
  const int t16 = lane & 15, quad = lane >> 4;
  const int wv16 = wv * 16;
  const int q8 = (quad ^ ((t16 >> 1) & 3)) * 8;  // swizzled phys chunk for ds_read
  const int wm64 = wm * 64;
  const int wn64 = wn * 64;

  // staging: thread t -> row t>>2 (256 rows, one pass); phys chunk t&3 holds
  // logical chunk (t&3)^key(row), key = (row>>1)&3 = (t>>3)&3; dst lane-linear.
  const int sr = tid >> 2;
  const int sc = ((tid & 3) ^ ((tid >> 3) & 3)) * 8;
  const bf16* gA = A + (size_t)(rowBase + sr) * 4096 + sc;
  const bf16* gB = Bt + (size_t)(colBase + sr) * 4096 + sc;

  f32x4 acc[4][4];
  #pragma unroll
  for (int i = 0; i < 4; ++i)
    #pragma unroll
    for (int j = 0; j < 4; ++j) acc[i][j] = (f32x4){0.f, 0.f, 0.f, 0.f};

  auto stA = [&](int buf, int s, int k0) {
    async_lds16(gA + k0 + s * 32, &As[buf][s][wv16][0]);
  };
  auto stB = [&](int buf, int s, int k0) {
    async_lds16(gB + k0 + s * 32, &Bs[buf][s][wv16][0]);
  };

  bf16x8 Ra[4], Rb[4], B0[2], B1[2];
  auto rdA = [&](bf16x8* R, int buf, int s) {
    #pragma unroll
    for (int i = 0; i < 4; ++i)
      R[i] = *(const bf16x8*)&As[buf][s][wm64 + i * 16 + t16][q8];
  };
  auto rdB2 = [&](bf16x8* R, int buf, int s, int h) {
    #pragma unroll
    for (int j = 0; j < 2; ++j)
      R[j] = *(const bf16x8*)&Bs[buf][s][wn64 + (h * 2 + j) * 16 + t16][q8];
  };
  auto mfma8 = [&](const bf16x8* Av, const bf16x8* Bp, int h) {
    __builtin_amdgcn_s_setprio(1);
    #pragma unroll
    for (int i = 0; i < 4; ++i)
      #pragma unroll
      for (int j = 0; j < 2; ++j)
        acc[i][h * 2 + j] =
            __builtin_amdgcn_mfma_f32_16x16x32_bf16(Av[i], Bp[j], acc[i][h * 2 + j], 0, 0, 0);
    __builtin_amdgcn_s_setprio(0);
  };

  // prologue: t0 -> buf0 (4 halves), t1 -> buf1 (3 halves; Bs1 staged at first R1)
  stA(0, 0, 0); stB(0, 0, 0); stA(0, 1, 0); stB(0, 1, 0);
  stA(1, 0, 64); stB(1, 0, 64); stA(1, 1, 64);
  WAIT_VM(3);  // t0's 4 halves landed; t1's 3 stay in flight
  BAR();

  for (int it = 0; it < 31; ++it) {
    const int kb = it * 128;
    // R1: buf0 ks0 — same-region reads (drained by this region's mfma)
    rdA(Ra, 0, 0); rdB2(B0, 0, 0, 0); rdB2(B1, 0, 0, 1);
    stB(1, 1, kb + 64);   // t+1.Bs1 (old: read prev R7, drained prev bar)
    mfma8(Ra, B0, 0);
    BAR();
    // R2
    rdA(Rb, 0, 1);
    stA(0, 0, kb + 128);  // t+2.As0 (old Ra drained bar R1)
    mfma8(Ra, B1, 1);
    BAR();
    // R3
    rdB2(B0, 0, 1, 0); rdB2(B1, 0, 1, 1);
    stB(0, 0, kb + 128);  // t+2.Bs0 (old B0 bar R1, old B1 bar R2)
    mfma8(Rb, B0, 0);
    BAR();
    // R4
    stA(0, 1, kb + 128);  // t+2.As1 (Rb drained bar R3)
    mfma8(Rb, B1, 1);
    WAIT_VM(3);           // t+1 fully landed (R1's stage); buf1 read after barrier
    BAR();
    // R5: buf1 ks0
    rdA(Ra, 1, 0); rdB2(B0, 1, 0, 0); rdB2(B1, 1, 0, 1);
    stB(0, 1, kb + 128);  // t+2.Bs1 (B0 bar R3, B1 bar R4)
    mfma8(Ra, B0, 0);
    BAR();
    // R6
    rdA(Rb, 1, 1);
    stA(1, 0, kb + 192);  // t+3.As0 (Ra drained bar R5)
    mfma8(Ra, B1, 1);
    BAR();
    // R7
    rdB2(B0, 1, 1, 0); rdB2(B1, 1, 1, 1);
    stB(1, 0, kb + 192);  // t+3.Bs0 (B0 bar R5, B1 bar R6)
    mfma8(Rb, B0, 0);
    BAR();
    // R8
    stA(1, 1, kb + 192);  // t+3.As1 (Rb drained bar R7)
    mfma8(Rb, B1, 1);
    WAIT_VM(3);           // t+2 fully landed (R5's stage); buf0 read next R1
    BAR();
  }

  // epilogue: tiles 62 (buf0) and 63 (buf1); only remaining stage is t63.Bs1
  rdA(Ra, 0, 0); rdB2(B0, 0, 0, 0); rdB2(B1, 0, 0, 1);
  stB(1, 1, 4032);
  mfma8(Ra, B0, 0);
  BAR();
  rdA(Rb, 0, 1);
  mfma8(Ra, B1, 1);
  BAR();
  rdB2(B0, 0, 1, 0); rdB2(B1, 0, 1, 1);
  mfma8(Rb, B0, 0);
  BAR();
  mfma8(Rb, B1, 1);
  WAIT_VM(0);  // t63 fully landed
  BAR();
  rdA(Ra, 1, 0); rdB2(B0, 1, 0, 0); rdB2(B1, 1, 0, 1);
  mfma8(Ra, B0, 0);
  rdA(Rb, 1, 1);
  mfma8(Ra, B1, 1);
  rdB2(B0, 1, 1, 0); rdB2(B1, 1, 1, 1);
  mfma8(Rb, B0, 0);
  mfma8(Rb, B1, 1);

  // D: row = quad*4+rr (M dim), col = t16 (N dim)
  #pragma unroll
  for (int i = 0; i < 4; ++i) {
    const int row0 = rowBase + wm64 + i * 16 + quad * 4;
    #pragma unroll
    for (int j = 0; j < 4; ++j) {
      const int col = colBase + wn64 + j * 16 + t16;
      #pragma unroll
      for (int rr = 0; rr < 4; ++rr)
        C[(size_t)(row0 + rr) * 4096 + col] = (bf16)acc[i][j][rr];
    }
  }
  if (Ct) {  // transposed store: Ct[col][row], 4 contiguous bf16 (8B) per frag
    #pragma unroll
    for (int i = 0; i < 4; ++i) {
      const int row0 = rowBase + wm64 + i * 16 + quad * 4;
      #pragma unroll
      for (int j = 0; j < 4; ++j) {
        const int col = colBase + wn64 + j * 16 + t16;
        union { bf16 h[4]; uint2 u; } pk;
        #pragma unroll
        for (int rr = 0; rr < 4; ++rr) pk.h[rr] = (bf16)acc[i][j][rr];
        *(uint2*)(Ct + (size_t)col * 4096 + row0) = pk.u;
      }
    }
  }
}

// ---- mix: out[b][n][o] = sum_{kk<192} Acat[n][kk] * Wcat[o][kk] + bias[o]
// Round-6 LDS-staged version (best measured).
__global__ __launch_bounds__(256) void mix_k(const float* __restrict__ x, const bf16* __restrict__ XG1,
                                             const bf16* __restrict__ XG2, const bf16* __restrict__ Wc,
                                             const float* __restrict__ bias, float* __restrict__ out) {
  __shared__ bf16 sW[64 * 200];   // stride 200 (=400B, 16B-aligned rows)
  __shared__ bf16 sX[128 * 64];   // block-local Acat chunks, swizzled
  __shared__ bf16 sG1[128 * 64];
  __shared__ bf16 sG2[128 * 64];
  const int tid = threadIdx.x;
  const int nt = blockIdx.x, b = blockIdx.y;
  const int nBase = nt * 128;
  const int lane = tid & 63, wv = tid >> 6;

  {  // Wc -> sW
    const int rw = tid >> 2, part = tid & 3;
    #pragma unroll
    for (int v = 0; v < 6; ++v)
      *(bf16x8*)(sW + rw * 200 + part * 48 + v * 8) = *(const bf16x8*)(Wc + rw * 192 + part * 48 + v * 8);
  }
  {  // XG1/XG2 -> sG1/sG2
    const int grow = tid >> 3, gc = tid & 7;
    const int gsrc = (gc ^ (grow & 7)) * 8;
    #pragma unroll
    for (int p = 0; p < 4; ++p) {
      const int r = grow + p * 32;
      async_lds16(XG1 + (size_t)(nBase + r) * 4096 + b * 64 + gsrc, sG1 + p * 2048 + wv * 512);
      async_lds16(XG2 + (size_t)(nBase + r) * 4096 + b * 64 + gsrc, sG2 + p * 2048 + wv * 512);
    }
  }
  {  // x -> sX coalesced + cvt + swizzled ds_write
    #pragma unroll
    for (int p = 0; p < 2; ++p) {
      const int idx = p * 256 + tid;
      const int r = idx >> 2, seg = idx & 3;
      const float* px = x + ((size_t)(b * 4096 + nBase + r)) * 64 + seg * 16;
      float4 f0 = *(const float4*)px;
      float4 f1 = *(const float4*)(px + 4);
      float4 f2 = *(const float4*)(px + 8);
      float4 f3 = *(const float4*)(px + 12);
      bf16x8 t0, t1;
      t0[0] = (bf16)f0.x; t0[1] = (bf16)f0.y; t0[2] = (bf16)f0.z; t0[3] = (bf16)f0.w;
      t0[4] = (bf16)f1.x; t0[5] = (bf16)f1.y; t0[6] = (bf16)f1.z; t0[7] = (bf16)f1.w;
      t1[0] = (bf16)f2.x; t1[1] = (bf16)f2.y; t1[2] = (bf16)f2.z; t1[3] = (bf16)f2.w;
      t1[4] = (bf16)f3.x; t1[5] = (bf16)f3.y; t1[6] = (bf16)f3.z; t1[7] = (bf16)f3.w;
      const int key = r & 7, c0 = seg * 2;
      *(bf16x8*)(sX + r * 64 + ((c0) ^ key) * 8) = t0;
      *(bf16x8*)(sX + r * 64 + ((c0 + 1) ^ key) * 8) = t1;
    }
  }
  __syncthreads();  // drains vmcnt (gload_lds) + lgkm (ds_writes)

  const int t16 = lane & 15, quad = lane >> 4;
  const int rloc = wv * 32;

  f32x4 acc[2][4];
  #pragma unroll
  for (int i = 0; i < 2; ++i)
    #pragma unroll
    for (int j = 0; j < 4; ++j) acc[i][j] = (f32x4){0.f, 0.f, 0.f, 0.f};

  #pragma unroll
  for (int ch = 0; ch < 6; ++ch) {
    const bf16* src = (ch < 2) ? sX : (ch < 4) ? sG1 : sG2;
    const int c = (ch & 1) * 4 + quad;
    bf16x8 a[2];
    #pragma unroll
    for (int i = 0; i < 2; ++i) {
      const int r = rloc + i * 16 + t16;
      a[i] = *(const bf16x8*)(src + r * 64 + ((c ^ (r & 7)) * 8));
    }
    #pragma unroll
    for (int j = 0; j < 4; ++j) {
      bf16x8 wf = *(const bf16x8*)(sW + (j * 16 + t16) * 200 + ch * 32 + quad * 8);
      #pragma unroll
      for (int i = 0; i < 2; ++i)
        acc[i][j] = __builtin_amdgcn_mfma_f32_16x16x32_bf16(a[i], wf, acc[i][j], 0, 0, 0);
    }
  }

  #pragma unroll
  for (int j = 0; j < 4; ++j) {
    const float bb = bias[j * 16 + t16];
    #pragma unroll
    for (int i = 0; i < 2; ++i) {
      const int n0 = nBase + wv * 32 + i * 16 + quad * 4;
      #pragma unroll
      for (int rr = 0; rr < 4; ++rr)
        out[(b * 4096 + n0 + rr) * 64 + j * 16 + t16] = acc[i][j][rr] + bb;
    }
  }
}

extern "C" void kernel_launch(void* const* d_in, const int* in_sizes, int n_in,
                              void* d_out, int out_size, void* d_ws, size_t ws_size,
                              hipStream_t stream) {
  const float* x    = (const float*)d_in[0];  // [64,4096,64]
  const float* adj  = (const float*)d_in[1];  // [4096,16]
  const float* emb  = (const float*)d_in[2];  // [16,4096]
  const float* w    = (const float*)d_in[3];  // [3,64,64]
  const float* bias = (const float*)d_in[4];  // [64]
  float* out = (float*)d_out;

  char* ws = (char*)d_ws;
  const size_t SZ = (size_t)4096 * 4096 * sizeof(bf16);  // 32 MiB
  bf16* S    = (bf16*)(ws);            // [n][m]
  bf16* XG1  = (bf16*)(ws + SZ);       // [n][bc]
  bf16* XG2  = (bf16*)(ws + 2 * SZ);   // [n][bc]
  bf16* XBUF = (bf16*)(ws + 3 * SZ);   // Xt [bc][m] (and XG1t fallback)
  const bool fused_t = ws_size >= 5 * SZ + (size_t)(64 * 192 * sizeof(bf16));
  bf16* XG1T = fused_t ? (bf16*)(ws + 4 * SZ) : XBUF;  // [bc][m]
  bf16* Wc   = (bf16*)(ws + (fused_t ? 5 : 4) * SZ);   // [64][192]

  pre_k<<<4608, 256, 0, stream>>>(adj, emb, S, w, Wc, x, XBUF);  // supports+wcat+xpose
  gemm256w16_k<<<256, 1024, 0, stream>>>(S, XBUF, XG1, fused_t ? XG1T : nullptr);
  if (!fused_t) transpose_bf16_k<<<4096, 256, 0, stream>>>(XG1, XBUF);  // XG1t
  gemm256w16_k<<<256, 1024, 0, stream>>>(S, XG1T, XG2, nullptr);        // XG2 = S @ XG1
  mix_k<<<dim3(32, 64), 256, 0, stream>>>(x, XG1, XG2, Wc, bias, out);
}